// Round 13
// baseline (133.963 us; speedup 1.0000x reference)
//
#include <hip/hip_runtime.h>
#include <hip/hip_bf16.h>
#include <math.h>

#define BB 2
#define HH 8
#define NN 4096
#define DD 64
#define MID 512
#define NOUT 512
#define QB 128          // q rows per block (4 waves x 32)
#define KVT 64          // kv rows per tile
#define NT (NN / KVT)
#define LOG2E 1.44269504088896340736f
#define SCALE 0.125f

typedef __attribute__((ext_vector_type(8)))  short bf16x8;
typedef __attribute__((ext_vector_type(4)))  float f32x4;
typedef __attribute__((ext_vector_type(16))) float f32x16;

__device__ __forceinline__ short f2bf(float x) {
  unsigned u = __builtin_bit_cast(unsigned, x);
  u = (u + 0x7FFFu + ((u >> 16) & 1u)) >> 16;
  return (short)u;
}

// faithful port of _relative_position_bucket (num_buckets=64, max_distance=128)
__device__ __forceinline__ int rp_bucket(int rel) {
  int ret = (rel >= 0) ? 32 : 0;
  int n = (rel >= 0) ? rel : -rel;
  if (n < 16) return ret + n;
  float nf = (float)n;
  float vf = 16.0f + (logf(nf * (1.0f / 16.0f)) / 2.0794415416798357f) * 16.0f;
  int vi = (int)vf;
  vi = vi < 31 ? vi : 31;
  return ret + vi;
}

__device__ __forceinline__ unsigned cvtpk(float lo, float hi) {
  unsigned d;
  asm("v_cvt_pk_bf16_f32 %0, %1, %2" : "=v"(d) : "v"(lo), "v"(hi));
  return d;
}

// async global->LDS, 16B per lane; LDS dest = wave-uniform base + lane*16
__device__ __forceinline__ void gl2lds16(const void* g, void* l) {
  __builtin_amdgcn_global_load_lds(
      (const __attribute__((address_space(1))) unsigned*)g,
      (__attribute__((address_space(3))) unsigned*)l, 16, 0, 0);
}

// fused pre-pass: K conversion + V transpose + W transpose, one launch
__global__ __launch_bounds__(256) void prep_kernel(
    const float* __restrict__ W,  short* __restrict__ Wt,
    const float* __restrict__ K,  short* __restrict__ Kws,
    const float* __restrict__ V,  short* __restrict__ Vtws)
{
  const int bx = blockIdx.x;
  const int t  = threadIdx.x;
  if (bx < 2048) {
    // K -> bf16 [bh][n][d], 16B slots XOR-permuted: slot_pos = a ^ (n&7)
    int i = bx * 256 + t;          // 524288 units of 8 f32
    int a = i & 7;
    int h = (i >> 3) & 7;
    int n = (i >> 6) & 4095;
    int b = i >> 18;
    const float* src = K + ((size_t)(b * 4096 + n) * 512 + h * 64 + a * 8);
    float4 x0 = *(const float4*)src;
    float4 x1 = *(const float4*)(src + 4);
    union { unsigned u[4]; bf16x8 v; } pk;
    pk.u[0] = cvtpk(x0.x, x0.y); pk.u[1] = cvtpk(x0.z, x0.w);
    pk.u[2] = cvtpk(x1.x, x1.y); pk.u[3] = cvtpk(x1.z, x1.w);
    size_t off = ((size_t)(b * 8 + h) * 4096 + n) * 64 + (size_t)((a ^ (n & 7)) * 8);
    *(bf16x8*)(Kws + off) = pk.v;
  } else if (bx < 3072) {
    // V -> bf16 transposed [bh][d][n], 16B-slot XOR-permute + sigma-permutation
    __shared__ short Vl[64][72];
    const int idx = bx - 2048;
    const int g = idx & 63;        // n-tile
    const int bh = idx >> 6;       // 0..15
    const int b = bh >> 3, h = bh & 7;
    const int c4 = t & 15, r = t >> 4;
    #pragma unroll
    for (int rr = 0; rr < 4; ++rr) {
      int nl = r + rr * 16;
      const float* src = V + ((size_t)(b * 4096 + g * 64 + nl) * 512 + h * 64 + c4 * 4);
      float4 x = *(const float4*)src;
      unsigned lo = cvtpk(x.x, x.y), hi2 = cvtpk(x.z, x.w);
      unsigned* dst = (unsigned*)&Vl[nl][c4 * 4];
      dst[0] = lo; dst[1] = hi2;
    }
    __syncthreads();
    #pragma unroll
    for (int it = 0; it < 2; ++it) {
      int u = t + it * 256;        // 0..511: d(6b) x stored-slot(3b)
      int d = u >> 3, sp = u & 7;
      int s = sp ^ (d & 7);        // logical slot
      union { short s[8]; bf16x8 v; } pk;
      #pragma unroll
      for (int e = 0; e < 8; ++e) {
        int np  = s * 8 + e;       // logical position 0..63
        int p16 = np & 15;
        int kvl = (np & 48) | (4 * (p16 >> 3) + (p16 & 3) + 8 * ((p16 >> 2) & 1));
        pk.s[e] = Vl[kvl][d];
      }
      *(bf16x8*)(Vtws + ((size_t)bh * 64 + d) * 4096 + g * 64 + sp * 8) = pk.v;
    }
  } else {
    // W[kin][n] -> Wt[n][kin] bf16 via LDS 64x64 tile transpose
    __shared__ short Wl[64][72];
    const int idx = bx - 3072;     // 0..63
    const int k0 = (idx & 7) * 64;
    const int n0 = (idx >> 3) * 64;
    const int c4 = t & 15, r = t >> 4;
    #pragma unroll
    for (int rr = 0; rr < 4; ++rr) {
      int kl = r + rr * 16;
      const float* src = W + (size_t)(k0 + kl) * 512 + n0 + c4 * 4;
      float4 x = *(const float4*)src;
      unsigned lo = cvtpk(x.x, x.y), hi2 = cvtpk(x.z, x.w);
      unsigned* dst = (unsigned*)&Wl[kl][c4 * 4];
      dst[0] = lo; dst[1] = hi2;
    }
    __syncthreads();
    #pragma unroll
    for (int it = 0; it < 2; ++it) {
      int u = t + it * 256;        // n_local(6b) x slot(3b)
      int nl = u >> 3, a = u & 7;
      union { short s[8]; bf16x8 v; } pk;
      #pragma unroll
      for (int e = 0; e < 8; ++e) pk.s[e] = Wl[a * 8 + e][nl];
      *(bf16x8*)(Wt + (size_t)(n0 + nl) * 512 + k0 + a * 8) = pk.v;
    }
  }
}

__global__ __launch_bounds__(256, 2) void attn_kernel(
    const float* __restrict__ q, const short* __restrict__ kws,
    const short* __restrict__ vtws, const float* __restrict__ table,
    short* __restrict__ attn_out)
{
  __shared__ short Ks[4][4096];   // 4-deep: [kv][d] bf16, slot-swizzled
  __shared__ short Vs[4][4096];   // 4-deep: [d][n'] bf16, slot-swizzled + sigma
  __shared__ float biasb[512];
  __shared__ float Lw[4][32];

  const int tid = threadIdx.x;
  const int w   = tid >> 6;
  const int l   = tid & 63;
  const int lq  = l & 31;
  const int hi  = l >> 5;

  // XCD-locality remap: xcd = raw&7 owns bh pair {2x, 2x+1}
  const int raw = blockIdx.x;                 // 0..511
  const int bh  = (raw & 7) * 2 + (raw >> 8);
  const int xb  = (raw >> 3) & 31;
  const int b = bh >> 3, h = bh & 7;
  const int q0 = xb * QB;
  const int qw = q0 + w * 32;
  const int qg = qw + lq;

  const float smul = SCALE * LOG2E;

  for (int i = tid; i < 512; i += 256)
    biasb[i] = table[rp_bucket(i - 256) * HH + h] * smul;
  const float c_lo = table[31 * HH + h] * smul;
  const float c_hi = table[63 * HH + h] * smul;

  f32x16 c16h, c16l;
  #pragma unroll
  for (int r = 0; r < 16; ++r) { c16h[r] = c_hi; c16l[r] = c_lo; }

  // ---- Q B-frags (pre-scaled): col=q=lq, k-slot = dc*16 + hi*8 + j ----
  bf16x8 qf[4];
  {
    const float* qr = q + ((size_t)b * NN + qg) * MID + (size_t)h * DD;
    #pragma unroll
    for (int dc = 0; dc < 4; ++dc) {
      int d0 = dc * 16 + hi * 8;
      float4 a0 = *(const float4*)(qr + d0);
      float4 a1 = *(const float4*)(qr + d0 + 4);
      bf16x8 f;
      f[0] = f2bf(a0.x * smul); f[1] = f2bf(a0.y * smul);
      f[2] = f2bf(a0.z * smul); f[3] = f2bf(a0.w * smul);
      f[4] = f2bf(a1.x * smul); f[5] = f2bf(a1.y * smul);
      f[6] = f2bf(a1.z * smul); f[7] = f2bf(a1.w * smul);
      qf[dc] = f;
    }
  }

  const short* kbh = kws  + (size_t)bh * NN * DD;
  const short* vbh = vtws + (size_t)bh * DD * NN;

  f32x16 o0a = {}, o0b = {}, o1a = {}, o1b = {};
  float ls0 = 0.f, ls1 = 0.f, ls2 = 0.f, ls3 = 0.f;

  // incremental per-lane staging pointers
  const int o1w = w * 1024 + l * 16;
  const int o2w = o1w + 4096;
  const char* pkA = (const char*)kbh + o1w;
  const char* pvA = (const char*)vbh + (size_t)(o1w >> 7) * 8192 + (o1w & 127);
  const char* pvB = (const char*)vbh + (size_t)(o2w >> 7) * 8192 + (o2w & 127);
  char* ldsK = (char*)&Ks[0][0] + w * 1024;
  char* ldsV = (char*)&Vs[0][0] + w * 1024;
  const char* kbase = (const char*)&Ks[0][0];
  const char* vbase = (const char*)&Vs[0][0];
  const int swz = lq & 7;

  bf16x8 pa0, pa1, pa2, pa3;    // P fragments of tile t-1 (persist across barrier)

#define STAGE(BOFF) {                                   \
    gl2lds16(pkA,        ldsK + (BOFF));                \
    gl2lds16(pkA + 4096, ldsK + (BOFF) + 4096);         \
    gl2lds16(pvA,        ldsV + (BOFF));                \
    gl2lds16(pvB,        ldsV + (BOFF) + 4096);         \
    pkA += 8192; pvA += 128; pvB += 128; }

#define PVSTEP(BOFF) {                                                       \
    const char* vr0 = vbase + (BOFF) + lq * 128;                             \
    const char* vr1 = vr0 + 32 * 128;                                        \
    __builtin_amdgcn_s_setprio(1);                                           \
    bf16x8 vfa0 = *(const bf16x8*)(vr0 + (((hi + 0) ^ swz) << 4));           \
    bf16x8 vfb0 = *(const bf16x8*)(vr0 + (((hi + 2) ^ swz) << 4));           \
    bf16x8 vfa1 = *(const bf16x8*)(vr1 + (((hi + 0) ^ swz) << 4));           \
    bf16x8 vfb1 = *(const bf16x8*)(vr1 + (((hi + 2) ^ swz) << 4));           \
    o0a = __builtin_amdgcn_mfma_f32_32x32x16_bf16(pa0, vfa0, o0a, 0, 0, 0);  \
    o0b = __builtin_amdgcn_mfma_f32_32x32x16_bf16(pa1, vfb0, o0b, 0, 0, 0);  \
    o1a = __builtin_amdgcn_mfma_f32_32x32x16_bf16(pa0, vfa1, o1a, 0, 0, 0);  \
    o1b = __builtin_amdgcn_mfma_f32_32x32x16_bf16(pa1, vfb1, o1b, 0, 0, 0);  \
    bf16x8 vfa2 = *(const bf16x8*)(vr0 + (((hi + 4) ^ swz) << 4));           \
    bf16x8 vfb2 = *(const bf16x8*)(vr0 + (((hi + 6) ^ swz) << 4));           \
    bf16x8 vfa3 = *(const bf16x8*)(vr1 + (((hi + 4) ^ swz) << 4));           \
    bf16x8 vfb3 = *(const bf16x8*)(vr1 + (((hi + 6) ^ swz) << 4));           \
    o0a = __builtin_amdgcn_mfma_f32_32x32x16_bf16(pa2, vfa2, o0a, 0, 0, 0);  \
    o0b = __builtin_amdgcn_mfma_f32_32x32x16_bf16(pa3, vfb2, o0b, 0, 0, 0);  \
    o1a = __builtin_amdgcn_mfma_f32_32x32x16_bf16(pa2, vfa3, o1a, 0, 0, 0);  \
    o1b = __builtin_amdgcn_mfma_f32_32x32x16_bf16(pa3, vfb3, o1b, 0, 0, 0);  \
    __builtin_amdgcn_s_setprio(0); }

  STAGE(0);                        // tile 0 -> buf 0
  STAGE(8192);                     // tile 1 -> buf 1
  __syncthreads();                 // biasb visible; tiles 0,1 loaded (full drain)

  int bo    = 0;                   // QK buffer offset (tile t)
  int bo_st = 16384;               // stage target (tile t+2)

  for (int t = 0; t < NT; ++t) {
    if (t) {
      if (t + 1 < NT) asm volatile("s_waitcnt vmcnt(4)" ::: "memory");
      else            asm volatile("s_waitcnt vmcnt(0)" ::: "memory");
      __builtin_amdgcn_s_barrier();
      // ---- O += P(t-1) V(t-1) : uses pa regs + long-resident V buffer ----
      PVSTEP((bo + 24576) & 32767);
    }

    const int kv0 = t * KVT;

    // ---- S^T = K Q^T + bias(C-init) : two interleaved accumulate chains ----
    const char* kr0 = kbase + bo + lq * 128;
    const char* kr1 = kr0 + 32 * 128;
    bf16x8 kf00 = *(const bf16x8*)(kr0 + ((hi ^ swz) << 4));
    bf16x8 kf10 = *(const bf16x8*)(kr1 + ((hi ^ swz) << 4));

    const int lo_rel = kv0 - (qw + 31);
    const int hi_rel = kv0 + KVT - 1 - qw;
    f32x16 acc0, acc1;
    if (lo_rel > 127) {
      acc0 = __builtin_amdgcn_mfma_f32_32x32x16_bf16(kf00, qf[0], c16h, 0, 0, 0);
      acc1 = __builtin_amdgcn_mfma_f32_32x32x16_bf16(kf10, qf[0], c16h, 0, 0, 0);
    } else if (hi_rel < -127) {
      acc0 = __builtin_amdgcn_mfma_f32_32x32x16_bf16(kf00, qf[0], c16l, 0, 0, 0);
      acc1 = __builtin_amdgcn_mfma_f32_32x32x16_bf16(kf10, qf[0], c16l, 0, 0, 0);
    } else {
      const int bidx0 = kv0 - qg + 256;
      f32x16 g0, g1;
      #pragma unroll
      for (int r = 0; r < 16; ++r) {
        int cr = (r & 3) + 8 * (r >> 2) + 4 * hi;
        g0[r] = biasb[bidx0 + cr];
        g1[r] = biasb[bidx0 + 32 + cr];
      }
      acc0 = __builtin_amdgcn_mfma_f32_32x32x16_bf16(kf00, qf[0], g0, 0, 0, 0);
      acc1 = __builtin_amdgcn_mfma_f32_32x32x16_bf16(kf10, qf[0], g1, 0, 0, 0);
    }
    __builtin_amdgcn_s_setprio(1);
    #pragma unroll
    for (int dc = 1; dc < 4; ++dc) {
      bf16x8 kf0 = *(const bf16x8*)(kr0 + (((dc * 2 + hi) ^ swz) << 4));
      bf16x8 kf1 = *(const bf16x8*)(kr1 + (((dc * 2 + hi) ^ swz) << 4));
      acc0 = __builtin_amdgcn_mfma_f32_32x32x16_bf16(kf0, qf[dc], acc0, 0, 0, 0);
      acc1 = __builtin_amdgcn_mfma_f32_32x32x16_bf16(kf1, qf[dc], acc1, 0, 0, 0);
    }
    __builtin_amdgcn_s_setprio(0);

    // ---- raw v_exp_f32 softmax numerator ----
    float p0[16], p1[16];
    #pragma unroll
    for (int r = 0; r < 16; ++r) p0[r] = __builtin_amdgcn_exp2f(acc0[r]);
    #pragma unroll
    for (int r = 0; r < 16; ++r) p1[r] = __builtin_amdgcn_exp2f(acc1[r]);

    // ---- row-sum accumulate ----
    ls0 += ((p0[0] + p0[1]) + (p0[2] + p0[3])) + ((p0[4] + p0[5]) + (p0[6] + p0[7]));
    ls1 += ((p0[8] + p0[9]) + (p0[10] + p0[11])) + ((p0[12] + p0[13]) + (p0[14] + p0[15]));
    ls2 += ((p1[0] + p1[1]) + (p1[2] + p1[3])) + ((p1[4] + p1[5]) + (p1[6] + p1[7]));
    ls3 += ((p1[8] + p1[9]) + (p1[10] + p1[11])) + ((p1[12] + p1[13]) + (p1[14] + p1[15]));

    // ---- pack: pa[ks][j] = P[kv = ks*16 + (j&3) + 8*(j>>2) + 4*hi] ----
    {
      union { unsigned u[4]; bf16x8 v; } ua, ub, uc, ud;
      ua.u[0] = cvtpk(p0[0],  p0[1]);  ua.u[1] = cvtpk(p0[2],  p0[3]);
      ua.u[2] = cvtpk(p0[4],  p0[5]);  ua.u[3] = cvtpk(p0[6],  p0[7]);
      ub.u[0] = cvtpk(p0[8],  p0[9]);  ub.u[1] = cvtpk(p0[10], p0[11]);
      ub.u[2] = cvtpk(p0[12], p0[13]); ub.u[3] = cvtpk(p0[14], p0[15]);
      uc.u[0] = cvtpk(p1[0],  p1[1]);  uc.u[1] = cvtpk(p1[2],  p1[3]);
      uc.u[2] = cvtpk(p1[4],  p1[5]);  uc.u[3] = cvtpk(p1[6],  p1[7]);
      ud.u[0] = cvtpk(p1[8],  p1[9]);  ud.u[1] = cvtpk(p1[10], p1[11]);
      ud.u[2] = cvtpk(p1[12], p1[13]); ud.u[3] = cvtpk(p1[14], p1[15]);
      pa0 = ua.v; pa1 = ub.v; pa2 = uc.v; pa3 = ud.v;
    }

    // issue tile t+2 into buf (t+2)&3 (last read two regions ago -> safe)
    if (t + 2 < NT) { STAGE(bo_st); }
    bo_st = (bo_st + 8192) & 32767;
    bo    = (bo + 8192) & 32767;
  }

  // ---- tail: PV of the last tile ----
  PVSTEP((bo + 24576) & 32767);

  // ---- epilogue: merge chains, cross-half row sums, normalize, store bf16 ----
  f32x16 o0, o1;
  #pragma unroll
  for (int r = 0; r < 16; ++r) { o0[r] = o0a[r] + o0b[r]; o1[r] = o1a[r] + o1b[r]; }
  float lsum = (ls0 + ls1) + (ls2 + ls3);
  float tot = lsum + __shfl_xor(lsum, 32);
  if (l < 32) Lw[w][l] = tot;
  __syncthreads();
  float inv[16];
  #pragma unroll
  for (int g = 0; g < 4; ++g) {
    f32x4 t4 = *(const f32x4*)&Lw[w][g * 8 + hi * 4];
    inv[g * 4 + 0] = 1.0f / t4[0];
    inv[g * 4 + 1] = 1.0f / t4[1];
    inv[g * 4 + 2] = 1.0f / t4[2];
    inv[g * 4 + 3] = 1.0f / t4[3];
  }
  const size_t ob = ((size_t)b * NN + qw) * MID + (size_t)h * DD;
  #pragma unroll
  for (int r = 0; r < 16; ++r) {
    const int crow = (r & 3) + 8 * (r >> 2) + 4 * hi;
    short* orow = attn_out + ob + (size_t)crow * MID;
    orow[lq]      = f2bf(o0[r] * inv[r]);
    orow[32 + lq] = f2bf(o1[r] * inv[r]);
  }
#undef STAGE
#undef PVSTEP
}

__global__ __launch_bounds__(256) void proj_kernel(
    const short* __restrict__ A, const short* __restrict__ Wt,
    const float* __restrict__ bias, float* __restrict__ out)
{
  const int tid = threadIdx.x;
  const int w  = tid >> 6;
  const int l  = tid & 63;
  const int lr = l & 15;
  const int lg = l >> 4;
  // XCD-affine decode: xcd (bid&7) owns a 16-m-tile chunk (1 MB A slice in L2),
  // n-phase walks slowest so the A slice is reused across all 8 n0 values.
  const int bid = blockIdx.x;
  const int mt = (bid & 7) * 16 + ((bid >> 3) & 15);   // 0..127
  const int n0 = (bid >> 7) * 64;
  const int m0 = mt * 64 + w * 16;

  f32x4 acc[4] = {};
  const short* ar = A + (size_t)(m0 + lr) * MID + lg * 8;
  #pragma unroll
  for (int kk = 0; kk < MID; kk += 32) {
    bf16x8 af = *(const bf16x8*)(ar + kk);
    #pragma unroll
    for (int u = 0; u < 4; ++u) {
      bf16x8 bfr = *(const bf16x8*)(Wt + (size_t)(n0 + u * 16 + lr) * MID + kk + lg * 8);
      acc[u] = __builtin_amdgcn_mfma_f32_16x16x32_bf16(af, bfr, acc[u], 0, 0, 0);
    }
  }
  #pragma unroll
  for (int u = 0; u < 4; ++u) {
    float bb = bias[n0 + u * 16 + lr];
    #pragma unroll
    for (int r = 0; r < 4; ++r)
      out[(size_t)(m0 + lg * 4 + r) * NOUT + n0 + u * 16 + lr] = acc[u][r] + bb;
  }
}

extern "C" void kernel_launch(void* const* d_in, const int* in_sizes, int n_in,
                              void* d_out, int out_size, void* d_ws, size_t ws_size,
                              hipStream_t stream) {
  const float* q     = (const float*)d_in[0];
  const float* k     = (const float*)d_in[1];
  const float* v     = (const float*)d_in[2];
  const float* table = (const float*)d_in[3];
  const float* W     = (const float*)d_in[4];
  const float* bo    = (const float*)d_in[5];
  float* out = (float*)d_out;

  char* wsp = (char*)d_ws;
  short* attn_ws = (short*)wsp;                       wsp += (size_t)BB * NN * MID * 2; // 8 MB
  short* Wt      = (short*)wsp;                       wsp += (size_t)MID * NOUT * 2;    // 0.5 MB
  short* kws     = (short*)wsp;                       wsp += (size_t)BB * HH * NN * DD * 2; // 8.4 MB
  short* vtws    = (short*)wsp;                                                          // 8.4 MB

  hipLaunchKernelGGL(prep_kernel, dim3(3136), dim3(256), 0, stream,
                     W, Wt, k, kws, v, vtws);
  hipLaunchKernelGGL(attn_kernel, dim3(BB * HH * (NN / QB)), dim3(256), 0, stream,
                     q, kws, vtws, table, attn_ws);
  hipLaunchKernelGGL(proj_kernel, dim3(BB * NN / 64 * (NOUT / 64)), dim3(256), 0, stream,
                     attn_ws, Wt, bo, out);
}

// Round 14
// 133.618 us; speedup vs baseline: 1.0026x; 1.0026x over previous
//
#include <hip/hip_runtime.h>
#include <hip/hip_bf16.h>
#include <math.h>

#define BB 2
#define HH 8
#define NN 4096
#define DD 64
#define MID 512
#define NOUT 512
#define QB 128          // q rows per block (4 waves x 32)
#define TT 32           // barrier regions (128 kv each = 2 halves of 64)
#define LOG2E 1.44269504088896340736f
#define SCALE 0.125f

typedef __attribute__((ext_vector_type(8)))  short bf16x8;
typedef __attribute__((ext_vector_type(4)))  float f32x4;
typedef __attribute__((ext_vector_type(16))) float f32x16;

__device__ __forceinline__ short f2bf(float x) {
  unsigned u = __builtin_bit_cast(unsigned, x);
  u = (u + 0x7FFFu + ((u >> 16) & 1u)) >> 16;
  return (short)u;
}

// faithful port of _relative_position_bucket (num_buckets=64, max_distance=128)
__device__ __forceinline__ int rp_bucket(int rel) {
  int ret = (rel >= 0) ? 32 : 0;
  int n = (rel >= 0) ? rel : -rel;
  if (n < 16) return ret + n;
  float nf = (float)n;
  float vf = 16.0f + (logf(nf * (1.0f / 16.0f)) / 2.0794415416798357f) * 16.0f;
  int vi = (int)vf;
  vi = vi < 31 ? vi : 31;
  return ret + vi;
}

__device__ __forceinline__ unsigned cvtpk(float lo, float hi) {
  unsigned d;
  asm("v_cvt_pk_bf16_f32 %0, %1, %2" : "=v"(d) : "v"(lo), "v"(hi));
  return d;
}

// async global->LDS, 16B per lane; LDS dest = wave-uniform base + lane*16
__device__ __forceinline__ void gl2lds16(const void* g, void* l) {
  __builtin_amdgcn_global_load_lds(
      (const __attribute__((address_space(1))) unsigned*)g,
      (__attribute__((address_space(3))) unsigned*)l, 16, 0, 0);
}

// fused pre-pass: K conversion + V transpose + W transpose, one launch
__global__ __launch_bounds__(256) void prep_kernel(
    const float* __restrict__ W,  short* __restrict__ Wt,
    const float* __restrict__ K,  short* __restrict__ Kws,
    const float* __restrict__ V,  short* __restrict__ Vtws)
{
  const int bx = blockIdx.x;
  const int t  = threadIdx.x;
  if (bx < 2048) {
    // K -> bf16 [bh][n][d], 16B slots XOR-permuted: slot_pos = a ^ (n&7)
    int i = bx * 256 + t;          // 524288 units of 8 f32
    int a = i & 7;
    int h = (i >> 3) & 7;
    int n = (i >> 6) & 4095;
    int b = i >> 18;
    const float* src = K + ((size_t)(b * 4096 + n) * 512 + h * 64 + a * 8);
    float4 x0 = *(const float4*)src;
    float4 x1 = *(const float4*)(src + 4);
    union { unsigned u[4]; bf16x8 v; } pk;
    pk.u[0] = cvtpk(x0.x, x0.y); pk.u[1] = cvtpk(x0.z, x0.w);
    pk.u[2] = cvtpk(x1.x, x1.y); pk.u[3] = cvtpk(x1.z, x1.w);
    size_t off = ((size_t)(b * 8 + h) * 4096 + n) * 64 + (size_t)((a ^ (n & 7)) * 8);
    *(bf16x8*)(Kws + off) = pk.v;
  } else if (bx < 3072) {
    // V -> bf16 transposed [bh][d][n], 16B-slot XOR-permute + sigma-permutation
    __shared__ short Vl[64][72];
    const int idx = bx - 2048;
    const int g = idx & 63;        // n-tile
    const int bh = idx >> 6;       // 0..15
    const int b = bh >> 3, h = bh & 7;
    const int c4 = t & 15, r = t >> 4;
    #pragma unroll
    for (int rr = 0; rr < 4; ++rr) {
      int nl = r + rr * 16;
      const float* src = V + ((size_t)(b * 4096 + g * 64 + nl) * 512 + h * 64 + c4 * 4);
      float4 x = *(const float4*)src;
      unsigned lo = cvtpk(x.x, x.y), hi2 = cvtpk(x.z, x.w);
      unsigned* dst = (unsigned*)&Vl[nl][c4 * 4];
      dst[0] = lo; dst[1] = hi2;
    }
    __syncthreads();
    #pragma unroll
    for (int it = 0; it < 2; ++it) {
      int u = t + it * 256;        // 0..511: d(6b) x stored-slot(3b)
      int d = u >> 3, sp = u & 7;
      int s = sp ^ (d & 7);        // logical slot
      union { short s[8]; bf16x8 v; } pk;
      #pragma unroll
      for (int e = 0; e < 8; ++e) {
        int np  = s * 8 + e;       // logical position 0..63
        int p16 = np & 15;
        int kvl = (np & 48) | (4 * (p16 >> 3) + (p16 & 3) + 8 * ((p16 >> 2) & 1));
        pk.s[e] = Vl[kvl][d];
      }
      *(bf16x8*)(Vtws + ((size_t)bh * 64 + d) * 4096 + g * 64 + sp * 8) = pk.v;
    }
  } else {
    // W[kin][n] -> Wt[n][kin] bf16 via LDS 64x64 tile transpose
    __shared__ short Wl[64][72];
    const int idx = bx - 3072;     // 0..63
    const int k0 = (idx & 7) * 64;
    const int n0 = (idx >> 3) * 64;
    const int c4 = t & 15, r = t >> 4;
    #pragma unroll
    for (int rr = 0; rr < 4; ++rr) {
      int kl = r + rr * 16;
      const float* src = W + (size_t)(k0 + kl) * 512 + n0 + c4 * 4;
      float4 x = *(const float4*)src;
      unsigned lo = cvtpk(x.x, x.y), hi2 = cvtpk(x.z, x.w);
      unsigned* dst = (unsigned*)&Wl[kl][c4 * 4];
      dst[0] = lo; dst[1] = hi2;
    }
    __syncthreads();
    #pragma unroll
    for (int it = 0; it < 2; ++it) {
      int u = t + it * 256;        // n_local(6b) x slot(3b)
      int nl = u >> 3, a = u & 7;
      union { short s[8]; bf16x8 v; } pk;
      #pragma unroll
      for (int e = 0; e < 8; ++e) pk.s[e] = Wl[a * 8 + e][nl];
      *(bf16x8*)(Wt + (size_t)(n0 + nl) * 512 + k0 + a * 8) = pk.v;
    }
  }
}

__global__ __launch_bounds__(256, 2) void attn_kernel(
    const float* __restrict__ q, const short* __restrict__ kws,
    const short* __restrict__ vtws, const float* __restrict__ table,
    short* __restrict__ attn_out)
{
  __shared__ short Ks[2][8192];   // [buf][half*4096 + kv*64 + d] swizzled
  __shared__ short Vs[2][8192];   // [buf][half*4096 + d*64 + n'] swizzled + sigma
  __shared__ float biasb[512];
  __shared__ float Lw[4][32];

  const int tid = threadIdx.x;
  const int w   = tid >> 6;
  const int l   = tid & 63;
  const int lq  = l & 31;
  const int hi  = l >> 5;

  // XCD-locality remap: xcd = raw&7 owns bh pair {2x, 2x+1}
  const int raw = blockIdx.x;                 // 0..511
  const int bh  = (raw & 7) * 2 + (raw >> 8);
  const int xb  = (raw >> 3) & 31;
  const int b = bh >> 3, h = bh & 7;
  const int q0 = xb * QB;
  const int qw = q0 + w * 32;
  const int qg = qw + lq;

  const float smul = SCALE * LOG2E;

  for (int i = tid; i < 512; i += 256)
    biasb[i] = table[rp_bucket(i - 256) * HH + h] * smul;
  const float c_lo = table[31 * HH + h] * smul;
  const float c_hi = table[63 * HH + h] * smul;

  f32x16 c16h, c16l;
  #pragma unroll
  for (int r = 0; r < 16; ++r) { c16h[r] = c_hi; c16l[r] = c_lo; }

  // ---- Q B-frags (pre-scaled): col=q=lq, k-slot = dc*16 + hi*8 + j ----
  bf16x8 qf[4];
  {
    const float* qr = q + ((size_t)b * NN + qg) * MID + (size_t)h * DD;
    #pragma unroll
    for (int dc = 0; dc < 4; ++dc) {
      int d0 = dc * 16 + hi * 8;
      float4 a0 = *(const float4*)(qr + d0);
      float4 a1 = *(const float4*)(qr + d0 + 4);
      bf16x8 f;
      f[0] = f2bf(a0.x * smul); f[1] = f2bf(a0.y * smul);
      f[2] = f2bf(a0.z * smul); f[3] = f2bf(a0.w * smul);
      f[4] = f2bf(a1.x * smul); f[5] = f2bf(a1.y * smul);
      f[6] = f2bf(a1.z * smul); f[7] = f2bf(a1.w * smul);
      qf[dc] = f;
    }
  }

  const short* kbh = kws  + (size_t)bh * NN * DD;
  const short* vbh = vtws + (size_t)bh * DD * NN;

  f32x16 o0a = {}, o0b = {}, o1a = {}, o1b = {};
  float ls0 = 0.f, ls1 = 0.f, ls2 = 0.f, ls3 = 0.f;

  // incremental per-lane staging pointers
  const int o1w = w * 1024 + l * 16;
  const int o2w = o1w + 4096;
  const char* pkA = (const char*)kbh + o1w;
  const char* pvA = (const char*)vbh + (size_t)(o1w >> 7) * 8192 + (o1w & 127);
  const char* pvB = (const char*)vbh + (size_t)(o2w >> 7) * 8192 + (o2w & 127);
  char* ldsK = (char*)&Ks[0][0] + w * 1024;
  char* ldsV = (char*)&Vs[0][0] + w * 1024;
  const char* kbase = (const char*)&Ks[0][0];
  const char* vbase = (const char*)&Vs[0][0];
  const int swz = lq & 7;

// stage one 128-kv tile (16KB K + 16KB V) into buffer at byte offset BOFF
#define STAGE(BOFF) {                                   \
    gl2lds16(pkA,         ldsK + (BOFF));               \
    gl2lds16(pkA + 4096,  ldsK + (BOFF) + 4096);        \
    gl2lds16(pkA + 8192,  ldsK + (BOFF) + 8192);        \
    gl2lds16(pkA + 12288, ldsK + (BOFF) + 12288);       \
    gl2lds16(pvA,         ldsV + (BOFF));               \
    gl2lds16(pvB,         ldsV + (BOFF) + 4096);        \
    gl2lds16(pvA + 128,   ldsV + (BOFF) + 8192);        \
    gl2lds16(pvB + 128,   ldsV + (BOFF) + 12288);       \
    pkA += 16384; pvA += 256; pvB += 256; }

// one 64-kv half: QK+bias, exp, rowsum, pack, PV  (reads K/V at offset BO)
#define BODY(KV0, BO) {                                                      \
    const char* kr0 = kbase + (BO) + lq * 128;                               \
    const char* kr1 = kr0 + 32 * 128;                                        \
    bf16x8 kf00 = *(const bf16x8*)(kr0 + ((hi ^ swz) << 4));                 \
    bf16x8 kf10 = *(const bf16x8*)(kr1 + ((hi ^ swz) << 4));                 \
    const int lo_rel = (KV0) - (qw + 31);                                    \
    const int hi_rel = (KV0) + 63 - qw;                                      \
    f32x16 acc0, acc1;                                                       \
    if (lo_rel > 127) {                                                      \
      acc0 = __builtin_amdgcn_mfma_f32_32x32x16_bf16(kf00, qf[0], c16h, 0, 0, 0); \
      acc1 = __builtin_amdgcn_mfma_f32_32x32x16_bf16(kf10, qf[0], c16h, 0, 0, 0); \
    } else if (hi_rel < -127) {                                              \
      acc0 = __builtin_amdgcn_mfma_f32_32x32x16_bf16(kf00, qf[0], c16l, 0, 0, 0); \
      acc1 = __builtin_amdgcn_mfma_f32_32x32x16_bf16(kf10, qf[0], c16l, 0, 0, 0); \
    } else {                                                                 \
      const int bidx0 = (KV0) - qg + 256;                                    \
      f32x16 g0, g1;                                                         \
      _Pragma("unroll")                                                      \
      for (int r = 0; r < 16; ++r) {                                         \
        int cr = (r & 3) + 8 * (r >> 2) + 4 * hi;                            \
        g0[r] = biasb[bidx0 + cr];                                           \
        g1[r] = biasb[bidx0 + 32 + cr];                                      \
      }                                                                      \
      acc0 = __builtin_amdgcn_mfma_f32_32x32x16_bf16(kf00, qf[0], g0, 0, 0, 0); \
      acc1 = __builtin_amdgcn_mfma_f32_32x32x16_bf16(kf10, qf[0], g1, 0, 0, 0); \
    }                                                                        \
    __builtin_amdgcn_s_setprio(1);                                           \
    _Pragma("unroll")                                                        \
    for (int dc = 1; dc < 4; ++dc) {                                         \
      bf16x8 kf0 = *(const bf16x8*)(kr0 + (((dc * 2 + hi) ^ swz) << 4));     \
      bf16x8 kf1 = *(const bf16x8*)(kr1 + (((dc * 2 + hi) ^ swz) << 4));     \
      acc0 = __builtin_amdgcn_mfma_f32_32x32x16_bf16(kf0, qf[dc], acc0, 0, 0, 0); \
      acc1 = __builtin_amdgcn_mfma_f32_32x32x16_bf16(kf1, qf[dc], acc1, 0, 0, 0); \
    }                                                                        \
    __builtin_amdgcn_s_setprio(0);                                           \
    float p0[16], p1[16];                                                    \
    _Pragma("unroll")                                                        \
    for (int r = 0; r < 16; ++r) p0[r] = __builtin_amdgcn_exp2f(acc0[r]);    \
    _Pragma("unroll")                                                        \
    for (int r = 0; r < 16; ++r) p1[r] = __builtin_amdgcn_exp2f(acc1[r]);    \
    ls0 += ((p0[0] + p0[1]) + (p0[2] + p0[3])) + ((p0[4] + p0[5]) + (p0[6] + p0[7]));       \
    ls1 += ((p0[8] + p0[9]) + (p0[10] + p0[11])) + ((p0[12] + p0[13]) + (p0[14] + p0[15])); \
    ls2 += ((p1[0] + p1[1]) + (p1[2] + p1[3])) + ((p1[4] + p1[5]) + (p1[6] + p1[7]));       \
    ls3 += ((p1[8] + p1[9]) + (p1[10] + p1[11])) + ((p1[12] + p1[13]) + (p1[14] + p1[15])); \
    bf16x8 pa0, pa1, pa2, pa3;                                               \
    {                                                                        \
      union { unsigned u[4]; bf16x8 v; } ua, ub, uc, ud;                     \
      ua.u[0] = cvtpk(p0[0],  p0[1]);  ua.u[1] = cvtpk(p0[2],  p0[3]);       \
      ua.u[2] = cvtpk(p0[4],  p0[5]);  ua.u[3] = cvtpk(p0[6],  p0[7]);       \
      ub.u[0] = cvtpk(p0[8],  p0[9]);  ub.u[1] = cvtpk(p0[10], p0[11]);      \
      ub.u[2] = cvtpk(p0[12], p0[13]); ub.u[3] = cvtpk(p0[14], p0[15]);      \
      uc.u[0] = cvtpk(p1[0],  p1[1]);  uc.u[1] = cvtpk(p1[2],  p1[3]);       \
      uc.u[2] = cvtpk(p1[4],  p1[5]);  uc.u[3] = cvtpk(p1[6],  p1[7]);       \
      ud.u[0] = cvtpk(p1[8],  p1[9]);  ud.u[1] = cvtpk(p1[10], p1[11]);      \
      ud.u[2] = cvtpk(p1[12], p1[13]); ud.u[3] = cvtpk(p1[14], p1[15]);      \
      pa0 = ua.v; pa1 = ub.v; pa2 = uc.v; pa3 = ud.v;                        \
    }                                                                        \
    {                                                                        \
      const char* vr0 = vbase + (BO) + lq * 128;                             \
      const char* vr1 = vr0 + 32 * 128;                                      \
      __builtin_amdgcn_s_setprio(1);                                         \
      bf16x8 vfa0 = *(const bf16x8*)(vr0 + (((hi + 0) ^ swz) << 4));         \
      bf16x8 vfb0 = *(const bf16x8*)(vr0 + (((hi + 2) ^ swz) << 4));         \
      bf16x8 vfa1 = *(const bf16x8*)(vr1 + (((hi + 0) ^ swz) << 4));         \
      bf16x8 vfb1 = *(const bf16x8*)(vr1 + (((hi + 2) ^ swz) << 4));         \
      o0a = __builtin_amdgcn_mfma_f32_32x32x16_bf16(pa0, vfa0, o0a, 0, 0, 0); \
      o0b = __builtin_amdgcn_mfma_f32_32x32x16_bf16(pa1, vfb0, o0b, 0, 0, 0); \
      o1a = __builtin_amdgcn_mfma_f32_32x32x16_bf16(pa0, vfa1, o1a, 0, 0, 0); \
      o1b = __builtin_amdgcn_mfma_f32_32x32x16_bf16(pa1, vfb1, o1b, 0, 0, 0); \
      bf16x8 vfa2 = *(const bf16x8*)(vr0 + (((hi + 4) ^ swz) << 4));         \
      bf16x8 vfb2 = *(const bf16x8*)(vr0 + (((hi + 6) ^ swz) << 4));         \
      bf16x8 vfa3 = *(const bf16x8*)(vr1 + (((hi + 4) ^ swz) << 4));         \
      bf16x8 vfb3 = *(const bf16x8*)(vr1 + (((hi + 6) ^ swz) << 4));         \
      o0a = __builtin_amdgcn_mfma_f32_32x32x16_bf16(pa2, vfa2, o0a, 0, 0, 0); \
      o0b = __builtin_amdgcn_mfma_f32_32x32x16_bf16(pa3, vfb2, o0b, 0, 0, 0); \
      o1a = __builtin_amdgcn_mfma_f32_32x32x16_bf16(pa2, vfa3, o1a, 0, 0, 0); \
      o1b = __builtin_amdgcn_mfma_f32_32x32x16_bf16(pa3, vfb3, o1b, 0, 0, 0); \
      __builtin_amdgcn_s_setprio(0);                                         \
    } }

  STAGE(0);                                    // tile 0 -> buf 0
  asm volatile("s_waitcnt vmcnt(0)" ::: "memory");
  __syncthreads();                             // tile 0 + biasb ready

  for (int t = 0; t < TT; ++t) {
    const int bo = (t & 1) * 16384;
    if (t + 1 < TT) STAGE(((t + 1) & 1) * 16384);   // issue next tile early
    BODY(t * 128,      bo);
    BODY(t * 128 + 64, bo + 8192);
    if (t + 1 < TT) asm volatile("s_waitcnt vmcnt(0)" ::: "memory");
    __builtin_amdgcn_s_barrier();              // loads had full region to land
  }

  // ---- epilogue: merge chains, cross-half row sums, normalize, store bf16 ----
  f32x16 o0, o1;
  #pragma unroll
  for (int r = 0; r < 16; ++r) { o0[r] = o0a[r] + o0b[r]; o1[r] = o1a[r] + o1b[r]; }
  float lsum = (ls0 + ls1) + (ls2 + ls3);
  float tot = lsum + __shfl_xor(lsum, 32);
  if (l < 32) Lw[w][l] = tot;
  __syncthreads();
  float inv[16];
  #pragma unroll
  for (int g = 0; g < 4; ++g) {
    f32x4 t4 = *(const f32x4*)&Lw[w][g * 8 + hi * 4];
    inv[g * 4 + 0] = 1.0f / t4[0];
    inv[g * 4 + 1] = 1.0f / t4[1];
    inv[g * 4 + 2] = 1.0f / t4[2];
    inv[g * 4 + 3] = 1.0f / t4[3];
  }
  const size_t ob = ((size_t)b * NN + qw) * MID + (size_t)h * DD;
  #pragma unroll
  for (int r = 0; r < 16; ++r) {
    const int crow = (r & 3) + 8 * (r >> 2) + 4 * hi;
    short* orow = attn_out + ob + (size_t)crow * MID;
    orow[lq]      = f2bf(o0[r] * inv[r]);
    orow[32 + lq] = f2bf(o1[r] * inv[r]);
  }
#undef STAGE
#undef BODY
}

__global__ __launch_bounds__(256) void proj_kernel(
    const short* __restrict__ A, const short* __restrict__ Wt,
    const float* __restrict__ bias, float* __restrict__ out)
{
  const int tid = threadIdx.x;
  const int w  = tid >> 6;
  const int l  = tid & 63;
  const int lr = l & 15;
  const int lg = l >> 4;
  // XCD-affine decode: xcd (bid&7) owns a 16-m-tile chunk (1 MB A slice in L2),
  // n-phase walks slowest so the A slice is reused across all 8 n0 values.
  const int bid = blockIdx.x;
  const int mt = (bid & 7) * 16 + ((bid >> 3) & 15);   // 0..127
  const int n0 = (bid >> 7) * 64;
  const int m0 = mt * 64 + w * 16;

  f32x4 acc[4] = {};
  const short* ar = A + (size_t)(m0 + lr) * MID + lg * 8;
  #pragma unroll
  for (int kk = 0; kk < MID; kk += 32) {
    bf16x8 af = *(const bf16x8*)(ar + kk);
    #pragma unroll
    for (int u = 0; u < 4; ++u) {
      bf16x8 bfr = *(const bf16x8*)(Wt + (size_t)(n0 + u * 16 + lr) * MID + kk + lg * 8);
      acc[u] = __builtin_amdgcn_mfma_f32_16x16x32_bf16(af, bfr, acc[u], 0, 0, 0);
    }
  }
  #pragma unroll
  for (int u = 0; u < 4; ++u) {
    float bb = bias[n0 + u * 16 + lr];
    #pragma unroll
    for (int r = 0; r < 4; ++r)
      out[(size_t)(m0 + lg * 4 + r) * NOUT + n0 + u * 16 + lr] = acc[u][r] + bb;
  }
}

extern "C" void kernel_launch(void* const* d_in, const int* in_sizes, int n_in,
                              void* d_out, int out_size, void* d_ws, size_t ws_size,
                              hipStream_t stream) {
  const float* q     = (const float*)d_in[0];
  const float* k     = (const float*)d_in[1];
  const float* v     = (const float*)d_in[2];
  const float* table = (const float*)d_in[3];
  const float* W     = (const float*)d_in[4];
  const float* bo    = (const float*)d_in[5];
  float* out = (float*)d_out;

  char* wsp = (char*)d_ws;
  short* attn_ws = (short*)wsp;                       wsp += (size_t)BB * NN * MID * 2; // 8 MB
  short* Wt      = (short*)wsp;                       wsp += (size_t)MID * NOUT * 2;    // 0.5 MB
  short* kws     = (short*)wsp;                       wsp += (size_t)BB * HH * NN * DD * 2; // 8.4 MB
  short* vtws    = (short*)wsp;                                                          // 8.4 MB

  hipLaunchKernelGGL(prep_kernel, dim3(3136), dim3(256), 0, stream,
                     W, Wt, k, kws, v, vtws);
  hipLaunchKernelGGL(attn_kernel, dim3(BB * HH * (NN / QB)), dim3(256), 0, stream,
                     q, kws, vtws, table, attn_ws);
  hipLaunchKernelGGL(proj_kernel, dim3(BB * NN / 64 * (NOUT / 64)), dim3(256), 0, stream,
                     attn_ws, Wt, bo, out);
}

// Round 15
// 121.393 us; speedup vs baseline: 1.1035x; 1.1007x over previous
//
#include <hip/hip_runtime.h>
#include <hip/hip_bf16.h>
#include <math.h>

#define BB 2
#define HH 8
#define NN 4096
#define DD 64
#define MID 512
#define NOUT 512
#define QB 128          // q rows per block (4 waves x 32)
#define KVT 64          // kv rows per tile
#define NT (NN / KVT)
#define LOG2E 1.44269504088896340736f
#define SCALE 0.125f

typedef __attribute__((ext_vector_type(8)))  short bf16x8;
typedef __attribute__((ext_vector_type(4)))  float f32x4;
typedef __attribute__((ext_vector_type(16))) float f32x16;

__device__ __forceinline__ short f2bf(float x) {
  unsigned u = __builtin_bit_cast(unsigned, x);
  u = (u + 0x7FFFu + ((u >> 16) & 1u)) >> 16;
  return (short)u;
}

// faithful port of _relative_position_bucket (num_buckets=64, max_distance=128)
__device__ __forceinline__ int rp_bucket(int rel) {
  int ret = (rel >= 0) ? 32 : 0;
  int n = (rel >= 0) ? rel : -rel;
  if (n < 16) return ret + n;
  float nf = (float)n;
  float vf = 16.0f + (logf(nf * (1.0f / 16.0f)) / 2.0794415416798357f) * 16.0f;
  int vi = (int)vf;
  vi = vi < 31 ? vi : 31;
  return ret + vi;
}

__device__ __forceinline__ unsigned cvtpk(float lo, float hi) {
  unsigned d;
  asm("v_cvt_pk_bf16_f32 %0, %1, %2" : "=v"(d) : "v"(lo), "v"(hi));
  return d;
}

// async global->LDS, 16B per lane; LDS dest = wave-uniform base + lane*16
__device__ __forceinline__ void gl2lds16(const void* g, void* l) {
  __builtin_amdgcn_global_load_lds(
      (const __attribute__((address_space(1))) unsigned*)g,
      (__attribute__((address_space(3))) unsigned*)l, 16, 0, 0);
}

// fused pre-pass: K conversion + V transpose + W transpose, one launch
__global__ __launch_bounds__(256) void prep_kernel(
    const float* __restrict__ W,  short* __restrict__ Wt,
    const float* __restrict__ K,  short* __restrict__ Kws,
    const float* __restrict__ V,  short* __restrict__ Vtws)
{
  const int bx = blockIdx.x;
  const int t  = threadIdx.x;
  if (bx < 2048) {
    // K -> bf16 [bh][n][d], 16B slots XOR-permuted: slot_pos = a ^ (n&7)
    // index map: wave's 8-lane groups cover all 8 slots of one n => 1KB/wave writes
    int i = bx * 256 + t;          // 524288 units of 8 f32
    int a = i & 7;
    int n = (i >> 3) & 4095;
    int h = (i >> 15) & 7;
    int b = i >> 18;
    const float* src = K + ((size_t)(b * 4096 + n) * 512 + h * 64 + a * 8);
    float4 x0 = *(const float4*)src;
    float4 x1 = *(const float4*)(src + 4);
    union { unsigned u[4]; bf16x8 v; } pk;
    pk.u[0] = cvtpk(x0.x, x0.y); pk.u[1] = cvtpk(x0.z, x0.w);
    pk.u[2] = cvtpk(x1.x, x1.y); pk.u[3] = cvtpk(x1.z, x1.w);
    size_t off = ((size_t)(b * 8 + h) * 4096 + n) * 64 + (size_t)((a ^ (n & 7)) * 8);
    *(bf16x8*)(Kws + off) = pk.v;
  } else if (bx < 2560) {
    // V -> bf16 transposed [bh][d][n]; TWO n-tiles per block so each d-row
    // write is 256B contiguous. 16B-slot XOR-permute + sigma-permutation.
    __shared__ short Vl[2][64][72];
    const int idx = bx - 2048;     // 0..511
    const int g0 = (idx & 31) * 2; // first n-tile
    const int bh = idx >> 5;       // 0..15
    const int b = bh >> 3, h = bh & 7;
    const int c4 = t & 15, r = t >> 4;
    #pragma unroll
    for (int gg = 0; gg < 2; ++gg) {
      #pragma unroll
      for (int rr = 0; rr < 4; ++rr) {
        int nl = r + rr * 16;
        const float* src = V + ((size_t)(b * 4096 + (g0 + gg) * 64 + nl) * 512 + h * 64 + c4 * 4);
        float4 x = *(const float4*)src;
        unsigned lo = cvtpk(x.x, x.y), hi2 = cvtpk(x.z, x.w);
        unsigned* dst = (unsigned*)&Vl[gg][nl][c4 * 4];
        dst[0] = lo; dst[1] = hi2;
      }
    }
    __syncthreads();
    #pragma unroll
    for (int it = 0; it < 4; ++it) {
      int u = t + it * 256;        // 0..1023: d(6b) x gg(1b) x sp(3b)
      int d = u >> 4, q4 = u & 15;
      int gg = q4 >> 3, sp = q4 & 7;
      int s = sp ^ (d & 7);        // logical slot
      union { short s[8]; bf16x8 v; } pk;
      #pragma unroll
      for (int e = 0; e < 8; ++e) {
        int np  = s * 8 + e;       // logical position 0..63
        int p16 = np & 15;
        int kvl = (np & 48) | (4 * (p16 >> 3) + (p16 & 3) + 8 * ((p16 >> 2) & 1));
        pk.s[e] = Vl[gg][kvl][d];
      }
      *(bf16x8*)(Vtws + ((size_t)bh * 64 + d) * 4096 + (g0 + gg) * 64 + sp * 8) = pk.v;
    }
  } else {
    // W[kin][n] -> Wt[n][kin] bf16 via LDS 64x64 tile transpose
    __shared__ short Wl[64][72];
    const int idx = bx - 2560;     // 0..63
    const int k0 = (idx & 7) * 64;
    const int n0 = (idx >> 3) * 64;
    const int c4 = t & 15, r = t >> 4;
    #pragma unroll
    for (int rr = 0; rr < 4; ++rr) {
      int kl = r + rr * 16;
      const float* src = W + (size_t)(k0 + kl) * 512 + n0 + c4 * 4;
      float4 x = *(const float4*)src;
      unsigned lo = cvtpk(x.x, x.y), hi2 = cvtpk(x.z, x.w);
      unsigned* dst = (unsigned*)&Wl[kl][c4 * 4];
      dst[0] = lo; dst[1] = hi2;
    }
    __syncthreads();
    #pragma unroll
    for (int it = 0; it < 2; ++it) {
      int u = t + it * 256;        // n_local(6b) x slot(3b)
      int nl = u >> 3, a = u & 7;
      union { short s[8]; bf16x8 v; } pk;
      #pragma unroll
      for (int e = 0; e < 8; ++e) pk.s[e] = Wl[a * 8 + e][nl];
      *(bf16x8*)(Wt + (size_t)(n0 + nl) * 512 + k0 + a * 8) = pk.v;
    }
  }
}

__global__ __launch_bounds__(256, 2) void attn_kernel(
    const float* __restrict__ q, const short* __restrict__ kws,
    const short* __restrict__ vtws, const float* __restrict__ table,
    short* __restrict__ attn_out)
{
  __shared__ short Ks[3][4096];   // 3-deep: [kv][d] bf16, slot-swizzled
  __shared__ short Vs[3][4096];   // 3-deep: [d][n'] bf16, slot-swizzled + sigma
  __shared__ float biasb[512];
  __shared__ float Lw[4][32];

  const int tid = threadIdx.x;
  const int w   = tid >> 6;
  const int l   = tid & 63;
  const int lq  = l & 31;
  const int hi  = l >> 5;

  // XCD-locality remap: xcd = raw&7 owns bh pair {2x, 2x+1}
  const int raw = blockIdx.x;                 // 0..511
  const int bh  = (raw & 7) * 2 + (raw >> 8);
  const int xb  = (raw >> 3) & 31;
  const int b = bh >> 3, h = bh & 7;
  const int q0 = xb * QB;
  const int qw = q0 + w * 32;
  const int qg = qw + lq;

  const float smul = SCALE * LOG2E;

  for (int i = tid; i < 512; i += 256)
    biasb[i] = table[rp_bucket(i - 256) * HH + h] * smul;
  const float c_lo = table[31 * HH + h] * smul;
  const float c_hi = table[63 * HH + h] * smul;

  f32x16 c16h, c16l;
  #pragma unroll
  for (int r = 0; r < 16; ++r) { c16h[r] = c_hi; c16l[r] = c_lo; }

  // ---- Q B-frags (pre-scaled): col=q=lq, k-slot = dc*16 + hi*8 + j ----
  bf16x8 qf[4];
  {
    const float* qr = q + ((size_t)b * NN + qg) * MID + (size_t)h * DD;
    #pragma unroll
    for (int dc = 0; dc < 4; ++dc) {
      int d0 = dc * 16 + hi * 8;
      float4 a0 = *(const float4*)(qr + d0);
      float4 a1 = *(const float4*)(qr + d0 + 4);
      bf16x8 f;
      f[0] = f2bf(a0.x * smul); f[1] = f2bf(a0.y * smul);
      f[2] = f2bf(a0.z * smul); f[3] = f2bf(a0.w * smul);
      f[4] = f2bf(a1.x * smul); f[5] = f2bf(a1.y * smul);
      f[6] = f2bf(a1.z * smul); f[7] = f2bf(a1.w * smul);
      qf[dc] = f;
    }
  }

  const short* kbh = kws  + (size_t)bh * NN * DD;
  const short* vbh = vtws + (size_t)bh * DD * NN;

  f32x16 o0a = {}, o0b = {}, o1a = {}, o1b = {};
  float ls0 = 0.f, ls1 = 0.f, ls2 = 0.f, ls3 = 0.f;

  // incremental per-lane staging pointers
  const int o1w = w * 1024 + l * 16;
  const int o2w = o1w + 4096;
  const char* pkA = (const char*)kbh + o1w;
  const char* pvA = (const char*)vbh + (size_t)(o1w >> 7) * 8192 + (o1w & 127);
  const char* pvB = (const char*)vbh + (size_t)(o2w >> 7) * 8192 + (o2w & 127);
  char* ldsK = (char*)&Ks[0][0] + w * 1024;
  char* ldsV = (char*)&Vs[0][0] + w * 1024;
  const char* kbase = (const char*)&Ks[0][0];
  const char* vbase = (const char*)&Vs[0][0];

#define STAGE(BOFF) {                                   \
    gl2lds16(pkA,        ldsK + (BOFF));                \
    gl2lds16(pkA + 4096, ldsK + (BOFF) + 4096);         \
    gl2lds16(pvA,        ldsV + (BOFF));                \
    gl2lds16(pvB,        ldsV + (BOFF) + 4096);         \
    pkA += 8192; pvA += 128; pvB += 128; }

  __syncthreads();                 // biasb visible to all waves
  STAGE(0);                        // tile 0 -> buf 0
  STAGE(8192);                     // tile 1 -> buf 1

  int bo_cur = 0, bo_nxt = 16384;  // tile t+2 -> buf 2 first

  for (int t = 0; t < NT; ++t) {
    // counted vmcnt: allow next tile's 4 loads to stay in flight (T4)
    if (t + 1 < NT) asm volatile("s_waitcnt vmcnt(4)" ::: "memory");
    else            asm volatile("s_waitcnt vmcnt(0)" ::: "memory");
    __builtin_amdgcn_s_barrier();

    const int kv0 = t * KVT;

    // ---- S^T = K Q^T + bias(C-init) : two interleaved accumulate chains ----
    const char* kr0 = kbase + bo_cur + lq * 128;
    const char* kr1 = kr0 + 32 * 128;
    const int swz = lq & 7;
    bf16x8 kf00 = *(const bf16x8*)(kr0 + ((hi ^ swz) << 4));
    bf16x8 kf10 = *(const bf16x8*)(kr1 + ((hi ^ swz) << 4));

    const int lo_rel = kv0 - (qw + 31);
    const int hi_rel = kv0 + KVT - 1 - qw;
    f32x16 acc0, acc1;
    if (lo_rel > 127) {
      acc0 = __builtin_amdgcn_mfma_f32_32x32x16_bf16(kf00, qf[0], c16h, 0, 0, 0);
      acc1 = __builtin_amdgcn_mfma_f32_32x32x16_bf16(kf10, qf[0], c16h, 0, 0, 0);
    } else if (hi_rel < -127) {
      acc0 = __builtin_amdgcn_mfma_f32_32x32x16_bf16(kf00, qf[0], c16l, 0, 0, 0);
      acc1 = __builtin_amdgcn_mfma_f32_32x32x16_bf16(kf10, qf[0], c16l, 0, 0, 0);
    } else {
      const int bidx0 = kv0 - qg + 256;
      f32x16 g0, g1;
      #pragma unroll
      for (int r = 0; r < 16; ++r) {
        int cr = (r & 3) + 8 * (r >> 2) + 4 * hi;
        g0[r] = biasb[bidx0 + cr];
        g1[r] = biasb[bidx0 + 32 + cr];
      }
      acc0 = __builtin_amdgcn_mfma_f32_32x32x16_bf16(kf00, qf[0], g0, 0, 0, 0);
      acc1 = __builtin_amdgcn_mfma_f32_32x32x16_bf16(kf10, qf[0], g1, 0, 0, 0);
    }
    __builtin_amdgcn_s_setprio(1);
    #pragma unroll
    for (int dc = 1; dc < 4; ++dc) {
      bf16x8 kf0 = *(const bf16x8*)(kr0 + (((dc * 2 + hi) ^ swz) << 4));
      bf16x8 kf1 = *(const bf16x8*)(kr1 + (((dc * 2 + hi) ^ swz) << 4));
      acc0 = __builtin_amdgcn_mfma_f32_32x32x16_bf16(kf0, qf[dc], acc0, 0, 0, 0);
      acc1 = __builtin_amdgcn_mfma_f32_32x32x16_bf16(kf1, qf[dc], acc1, 0, 0, 0);
    }
    __builtin_amdgcn_s_setprio(0);

    // ---- raw v_exp_f32 softmax numerator ----
    float p0[16], p1[16];
    #pragma unroll
    for (int r = 0; r < 16; ++r) p0[r] = __builtin_amdgcn_exp2f(acc0[r]);
    #pragma unroll
    for (int r = 0; r < 16; ++r) p1[r] = __builtin_amdgcn_exp2f(acc1[r]);

    // ---- row-sum accumulate ----
    ls0 += ((p0[0] + p0[1]) + (p0[2] + p0[3])) + ((p0[4] + p0[5]) + (p0[6] + p0[7]));
    ls1 += ((p0[8] + p0[9]) + (p0[10] + p0[11])) + ((p0[12] + p0[13]) + (p0[14] + p0[15]));
    ls2 += ((p1[0] + p1[1]) + (p1[2] + p1[3])) + ((p1[4] + p1[5]) + (p1[6] + p1[7]));
    ls3 += ((p1[8] + p1[9]) + (p1[10] + p1[11])) + ((p1[12] + p1[13]) + (p1[14] + p1[15]));

    // ---- pack: pa[ks][j] = P[kv = ks*16 + (j&3) + 8*(j>>2) + 4*hi] ----
    bf16x8 pa[4];
    {
      union { unsigned u[4]; bf16x8 v; } ua, ub, uc, ud;
      ua.u[0] = cvtpk(p0[0],  p0[1]);  ua.u[1] = cvtpk(p0[2],  p0[3]);
      ua.u[2] = cvtpk(p0[4],  p0[5]);  ua.u[3] = cvtpk(p0[6],  p0[7]);
      ub.u[0] = cvtpk(p0[8],  p0[9]);  ub.u[1] = cvtpk(p0[10], p0[11]);
      ub.u[2] = cvtpk(p0[12], p0[13]); ub.u[3] = cvtpk(p0[14], p0[15]);
      uc.u[0] = cvtpk(p1[0],  p1[1]);  uc.u[1] = cvtpk(p1[2],  p1[3]);
      uc.u[2] = cvtpk(p1[4],  p1[5]);  uc.u[3] = cvtpk(p1[6],  p1[7]);
      ud.u[0] = cvtpk(p1[8],  p1[9]);  ud.u[1] = cvtpk(p1[10], p1[11]);
      ud.u[2] = cvtpk(p1[12], p1[13]); ud.u[3] = cvtpk(p1[14], p1[15]);
      pa[0] = ua.v; pa[1] = ub.v; pa[2] = uc.v; pa[3] = ud.v;
    }

    // ---- O += P V : 4 accumulator chains, B-frag = one swizzled ds_read_b128 ----
    {
      const char* vr0 = vbase + bo_cur + lq * 128;
      const char* vr1 = vr0 + 32 * 128;
      const int s0 = lq & 7;
      __builtin_amdgcn_s_setprio(1);
      #pragma unroll
      for (int ks = 0; ks < 4; ks += 2) {
        bf16x8 vfa0 = *(const bf16x8*)(vr0 + (((hi + 2 * ks) ^ s0) << 4));
        bf16x8 vfb0 = *(const bf16x8*)(vr0 + (((hi + 2 * (ks + 1)) ^ s0) << 4));
        bf16x8 vfa1 = *(const bf16x8*)(vr1 + (((hi + 2 * ks) ^ s0) << 4));
        bf16x8 vfb1 = *(const bf16x8*)(vr1 + (((hi + 2 * (ks + 1)) ^ s0) << 4));
        o0a = __builtin_amdgcn_mfma_f32_32x32x16_bf16(pa[ks],     vfa0, o0a, 0, 0, 0);
        o0b = __builtin_amdgcn_mfma_f32_32x32x16_bf16(pa[ks + 1], vfb0, o0b, 0, 0, 0);
        o1a = __builtin_amdgcn_mfma_f32_32x32x16_bf16(pa[ks],     vfa1, o1a, 0, 0, 0);
        o1b = __builtin_amdgcn_mfma_f32_32x32x16_bf16(pa[ks + 1], vfb1, o1b, 0, 0, 0);
      }
      __builtin_amdgcn_s_setprio(0);
    }

    // issue tile t+2 into the buffer last read at iter t-1 (all waves past
    // this iter's barrier => safe to overwrite)
    if (t + 2 < NT) STAGE(bo_nxt);
    bo_cur = (bo_cur == 16384) ? 0 : bo_cur + 8192;
    bo_nxt = (bo_nxt == 16384) ? 0 : bo_nxt + 8192;
  }

  // ---- epilogue: merge chains, cross-half row sums, normalize, store bf16 ----
  f32x16 o0, o1;
  #pragma unroll
  for (int r = 0; r < 16; ++r) { o0[r] = o0a[r] + o0b[r]; o1[r] = o1a[r] + o1b[r]; }
  float lsum = (ls0 + ls1) + (ls2 + ls3);
  float tot = lsum + __shfl_xor(lsum, 32);
  if (l < 32) Lw[w][l] = tot;
  __syncthreads();
  float inv[16];
  #pragma unroll
  for (int g = 0; g < 4; ++g) {
    f32x4 t4 = *(const f32x4*)&Lw[w][g * 8 + hi * 4];
    inv[g * 4 + 0] = 1.0f / t4[0];
    inv[g * 4 + 1] = 1.0f / t4[1];
    inv[g * 4 + 2] = 1.0f / t4[2];
    inv[g * 4 + 3] = 1.0f / t4[3];
  }
  const size_t ob = ((size_t)b * NN + qw) * MID + (size_t)h * DD;
  #pragma unroll
  for (int r = 0; r < 16; ++r) {
    const int crow = (r & 3) + 8 * (r >> 2) + 4 * hi;
    short* orow = attn_out + ob + (size_t)crow * MID;
    orow[lq]      = f2bf(o0[r] * inv[r]);
    orow[32 + lq] = f2bf(o1[r] * inv[r]);
  }
#undef STAGE
}

__global__ __launch_bounds__(256) void proj_kernel(
    const short* __restrict__ A, const short* __restrict__ Wt,
    const float* __restrict__ bias, float* __restrict__ out)
{
  const int tid = threadIdx.x;
  const int w  = tid >> 6;
  const int l  = tid & 63;
  const int lr = l & 15;
  const int lg = l >> 4;
  // Two m-tiles per block (B-frag reuse). XCD-affine: xcd (bid&7) owns 8
  // m-pairs (2MB A slice); n-phase slowest so the slice is reused 8x in L2.
  const int bid = blockIdx.x;                          // 0..511
  const int mp = (bid & 7) * 8 + ((bid >> 3) & 7);     // m-pair 0..63
  const int n0 = (bid >> 6) * 64;
  const int m0 = mp * 128 + w * 16;                    // first m-tile row
  const int m1 = m0 + 64;                              // second m-tile row

  f32x4 acc0[4] = {}, acc1[4] = {};
  const short* ar0 = A + (size_t)(m0 + lr) * MID + lg * 8;
  const short* ar1 = A + (size_t)(m1 + lr) * MID + lg * 8;
  #pragma unroll
  for (int kk = 0; kk < MID; kk += 32) {
    bf16x8 af0 = *(const bf16x8*)(ar0 + kk);
    bf16x8 af1 = *(const bf16x8*)(ar1 + kk);
    #pragma unroll
    for (int u = 0; u < 4; ++u) {
      bf16x8 bfr = *(const bf16x8*)(Wt + (size_t)(n0 + u * 16 + lr) * MID + kk + lg * 8);
      acc0[u] = __builtin_amdgcn_mfma_f32_16x16x32_bf16(af0, bfr, acc0[u], 0, 0, 0);
      acc1[u] = __builtin_amdgcn_mfma_f32_16x16x32_bf16(af1, bfr, acc1[u], 0, 0, 0);
    }
  }
  #pragma unroll
  for (int u = 0; u < 4; ++u) {
    float bb = bias[n0 + u * 16 + lr];
    #pragma unroll
    for (int r = 0; r < 4; ++r) {
      out[(size_t)(m0 + lg * 4 + r) * NOUT + n0 + u * 16 + lr] = acc0[u][r] + bb;
      out[(size_t)(m1 + lg * 4 + r) * NOUT + n0 + u * 16 + lr] = acc1[u][r] + bb;
    }
  }
}

extern "C" void kernel_launch(void* const* d_in, const int* in_sizes, int n_in,
                              void* d_out, int out_size, void* d_ws, size_t ws_size,
                              hipStream_t stream) {
  const float* q     = (const float*)d_in[0];
  const float* k     = (const float*)d_in[1];
  const float* v     = (const float*)d_in[2];
  const float* table = (const float*)d_in[3];
  const float* W     = (const float*)d_in[4];
  const float* bo    = (const float*)d_in[5];
  float* out = (float*)d_out;

  char* wsp = (char*)d_ws;
  short* attn_ws = (short*)wsp;                       wsp += (size_t)BB * NN * MID * 2; // 8 MB
  short* Wt      = (short*)wsp;                       wsp += (size_t)MID * NOUT * 2;    // 0.5 MB
  short* kws     = (short*)wsp;                       wsp += (size_t)BB * HH * NN * DD * 2; // 8.4 MB
  short* vtws    = (short*)wsp;                                                          // 8.4 MB

  hipLaunchKernelGGL(prep_kernel, dim3(2624), dim3(256), 0, stream,
                     W, Wt, k, kws, v, vtws);
  hipLaunchKernelGGL(attn_kernel, dim3(BB * HH * (NN / QB)), dim3(256), 0, stream,
                     q, kws, vtws, table, attn_ws);
  hipLaunchKernelGGL(proj_kernel, dim3(512), dim3(256), 0, stream,
                     attn_ws, Wt, bo, out);
}